// Round 3
// baseline (2869.759 us; speedup 1.0000x reference)
//
#include <hip/hip_runtime.h>
#include <math.h>

#define NTOT 8500

// ---------------------------------------------------------------------------
// Geometry: 4 scales concatenated along n: [6400 | 1600 | 400 | 100] = 8500.
// All boundaries divisible by 4 -> float4 loads never straddle scales.
// ---------------------------------------------------------------------------
__device__ __forceinline__ size_t in_index(int gn, int bc, int* which) {
  if (gn < 6400) { *which = 0; return (size_t)bc * 6400 + gn; }
  if (gn < 8000) { *which = 1; return (size_t)bc * 1600 + (gn - 6400); }
  if (gn < 8400) { *which = 2; return (size_t)bc * 400  + (gn - 8000); }
  *which = 3;     return (size_t)bc * 100  + (gn - 8400);
}

// ---------------------------------------------------------------------------
// conv kernel: per batch GEMM  out[o,n] = sum_c W[o,c] * X[c,n]  (+ epilogue)
// WHICH=0: conv1, X gathered from 4 input scales, +bias, write x_total
// WHICH=1: conv2, X = x_rec (contiguous), epilogue BN + residual + relu,
//          scattered writes into the 4 output scale segments of d_out
// tile: 64 (o) x 128 (n), 256 threads, thread = 4x8, K-chunks of 32
// ---------------------------------------------------------------------------
template <int WHICH>
__global__ __launch_bounds__(256)
void conv_kernel(const float* __restrict__ W, const float* __restrict__ bias,
                 const float* __restrict__ x0, const float* __restrict__ x1,
                 const float* __restrict__ x2, const float* __restrict__ x3,
                 const float* __restrict__ xrec,
                 const float* __restrict__ bn_g, const float* __restrict__ bn_b,
                 const float* __restrict__ bn_m, const float* __restrict__ bn_v,
                 float* __restrict__ out)
{
  __shared__ float As[32][68];    // [kk][o]
  __shared__ float Bs[32][132];   // [kk][n]
  const int t  = threadIdx.x;
  const int n0 = blockIdx.x * 128;
  const int m0 = blockIdx.y * 64;
  const int b  = blockIdx.z;
  const int tm = t & 15, tn = t >> 4;

  float acc[4][8];
#pragma unroll
  for (int i = 0; i < 4; ++i)
#pragma unroll
    for (int j = 0; j < 8; ++j) acc[i][j] = 0.f;

  for (int k0 = 0; k0 < 256; k0 += 32) {
#pragma unroll
    for (int it = 0; it < 2; ++it) {
      const int o_l = (t >> 3) + 32 * it;
      const int kk4 = (t & 7) * 4;
      float4 v = *(const float4*)(W + (size_t)(m0 + o_l) * 256 + k0 + kk4);
      As[kk4 + 0][o_l] = v.x; As[kk4 + 1][o_l] = v.y;
      As[kk4 + 2][o_l] = v.z; As[kk4 + 3][o_l] = v.w;
    }
#pragma unroll
    for (int it = 0; it < 4; ++it) {
      const int kk  = (t >> 5) + 8 * it;
      const int nn4 = (t & 31) * 4;
      const int gn  = n0 + nn4;
      float4 v = make_float4(0.f, 0.f, 0.f, 0.f);
      if (gn < NTOT) {
        if (WHICH == 0) {
          int w_; size_t idx = in_index(gn, b * 256 + k0 + kk, &w_);
          const float* src = (w_ == 0) ? x0 : (w_ == 1) ? x1 : (w_ == 2) ? x2 : x3;
          v = *(const float4*)(src + idx);
        } else {
          v = *(const float4*)(xrec + (size_t)(b * 256 + k0 + kk) * NTOT + gn);
        }
      }
      *(float4*)&Bs[kk][nn4] = v;
    }
    __syncthreads();
#pragma unroll
    for (int kk = 0; kk < 32; ++kk) {
      float4 a = *(const float4*)&As[kk][tm * 4];
      float4 p = *(const float4*)&Bs[kk][tn * 8];
      float4 q = *(const float4*)&Bs[kk][tn * 8 + 4];
      float av[4] = {a.x, a.y, a.z, a.w};
      float bv[8] = {p.x, p.y, p.z, p.w, q.x, q.y, q.z, q.w};
#pragma unroll
      for (int i = 0; i < 4; ++i)
#pragma unroll
        for (int j = 0; j < 8; ++j)
          acc[i][j] = fmaf(av[i], bv[j], acc[i][j]);
    }
    __syncthreads();
  }

#pragma unroll
  for (int i = 0; i < 4; ++i) {
    const int o = m0 + tm * 4 + i;
    float addb = 0.f, isf = 0.f, shf = 0.f;
    if (WHICH == 0) {
      addb = bias[o];
    } else {
      float g = bn_g[o];
      isf = g / sqrtf(bn_v[o] + 1e-5f);
      shf = bn_b[o] - bn_m[o] * isf;
    }
#pragma unroll
    for (int jj = 0; jj < 8; jj += 4) {
      const int gn = n0 + tn * 8 + jj;
      if (gn >= NTOT) continue;
      float4 r = make_float4(acc[i][jj + 0], acc[i][jj + 1],
                             acc[i][jj + 2], acc[i][jj + 3]);
      if (WHICH == 0) {
        r.x += addb; r.y += addb; r.z += addb; r.w += addb;
        *(float4*)(out + (size_t)(b * 256 + o) * NTOT + gn) = r;
      } else {
        int w_; size_t idx = in_index(gn, b * 256 + o, &w_);
        const float* src = (w_ == 0) ? x0 : (w_ == 1) ? x1 : (w_ == 2) ? x2 : x3;
        float4 rv = *(const float4*)(src + idx);
        size_t ob = (w_ == 0) ? 0ull : (w_ == 1) ? 26214400ull
                  : (w_ == 2) ? 32768000ull : 34406400ull;
        r.x = fmaxf(fmaf(r.x, isf, shf) + rv.x, 0.f);
        r.y = fmaxf(fmaf(r.y, isf, shf) + rv.y, 0.f);
        r.z = fmaxf(fmaf(r.z, isf, shf) + rv.z, 0.f);
        r.w = fmaxf(fmaf(r.w, isf, shf) + rv.w, 0.f);
        *(float4*)(out + ob + idx) = r;
      }
    }
  }
}

// ---------------------------------------------------------------------------
// z kernel: z[n,k] = softmax_k( sum_c xt[c,n] * mu[c,k] )
// tile: 128 n x 64 k, 256 threads, thread = 8n x 4k; row lanes contiguous
// (tk = t&15) so softmax reduces with 16-lane shuffles.
// ---------------------------------------------------------------------------
__global__ __launch_bounds__(256)
void z_kernel(const float* __restrict__ xt, const float* __restrict__ mu,
              int mu_per_batch, float* __restrict__ zbuf)
{
  __shared__ float xs[32][136];  // [cc][n]
  __shared__ float mus[32][68];  // [cc][k]
  const int t  = threadIdx.x;
  const int n0 = blockIdx.x * 128;
  const int b  = blockIdx.y;
  const float* mub = mu + (mu_per_batch ? (size_t)b * 256 * 64 : 0);
  const int tk = t & 15, tn = t >> 4;

  float acc[8][4];
#pragma unroll
  for (int r = 0; r < 8; ++r)
#pragma unroll
    for (int j = 0; j < 4; ++j) acc[r][j] = 0.f;

  for (int c0 = 0; c0 < 256; c0 += 32) {
#pragma unroll
    for (int it = 0; it < 4; ++it) {
      const int cc  = (t >> 5) + 8 * it;
      const int nn4 = (t & 31) * 4;
      const int gn  = n0 + nn4;
      float4 v = (gn < NTOT)
          ? *(const float4*)(xt + (size_t)(b * 256 + c0 + cc) * NTOT + gn)
          : make_float4(0.f, 0.f, 0.f, 0.f);
      *(float4*)&xs[cc][nn4] = v;
    }
#pragma unroll
    for (int it = 0; it < 2; ++it) {
      const int cc  = (t >> 4) + 16 * it;
      const int kk4 = (t & 15) * 4;
      float4 v = *(const float4*)(mub + (size_t)(c0 + cc) * 64 + kk4);
      *(float4*)&mus[cc][kk4] = v;
    }
    __syncthreads();
#pragma unroll
    for (int cc = 0; cc < 32; ++cc) {
      float4 m4 = *(const float4*)&mus[cc][tk * 4];
      float4 xa = *(const float4*)&xs[cc][tn * 8];
      float4 xb = *(const float4*)&xs[cc][tn * 8 + 4];
      float xv[8] = {xa.x, xa.y, xa.z, xa.w, xb.x, xb.y, xb.z, xb.w};
      float mv[4] = {m4.x, m4.y, m4.z, m4.w};
#pragma unroll
      for (int r = 0; r < 8; ++r)
#pragma unroll
        for (int j = 0; j < 4; ++j)
          acc[r][j] = fmaf(xv[r], mv[j], acc[r][j]);
    }
    __syncthreads();
  }

#pragma unroll
  for (int r = 0; r < 8; ++r) {
    float mx = fmaxf(fmaxf(acc[r][0], acc[r][1]), fmaxf(acc[r][2], acc[r][3]));
#pragma unroll
    for (int off = 8; off >= 1; off >>= 1) mx = fmaxf(mx, __shfl_xor(mx, off));
    float e0 = __expf(acc[r][0] - mx), e1 = __expf(acc[r][1] - mx);
    float e2 = __expf(acc[r][2] - mx), e3 = __expf(acc[r][3] - mx);
    float s = e0 + e1 + e2 + e3;
#pragma unroll
    for (int off = 8; off >= 1; off >>= 1) s += __shfl_xor(s, off);
    const float inv = 1.0f / s;
    const int gn = n0 + tn * 8 + r;
    if (gn < NTOT) {
      float4 w = make_float4(e0 * inv, e1 * inv, e2 * inv, e3 * inv);
      *(float4*)(zbuf + ((size_t)b * NTOT + gn) * 64 + tk * 4) = w;
    }
  }
}

// ---------------------------------------------------------------------------
// mu partial: part[b,ch,k,c] = sum_{n in chunk} xt[c,n] * z[n,k]
// (z-colsum normalization cancels in the downstream l2norm -> skipped)
// tile: 128 c x 64 k, 256 threads, thread = 8c x 4k, chunk = 512 n
// ---------------------------------------------------------------------------
__global__ __launch_bounds__(256)
void mu_part_kernel(const float* __restrict__ xt, const float* __restrict__ z,
                    float* __restrict__ part)
{
  __shared__ float As[32][132];  // [nn][c]
  __shared__ float Bs[32][68];   // [nn][k]
  const int t  = threadIdx.x;
  const int ch = blockIdx.x;         // 0..16
  const int c0 = blockIdx.y * 128;   // 0,128
  const int b  = blockIdx.z;
  const int nb = ch * 512;
  const int tk = t & 15, tc = t >> 4;

  float acc[8][4];
#pragma unroll
  for (int i = 0; i < 8; ++i)
#pragma unroll
    for (int j = 0; j < 4; ++j) acc[i][j] = 0.f;

  for (int kb = 0; kb < 512; kb += 32) {
#pragma unroll
    for (int it = 0; it < 4; ++it) {
      const int c_l = (t >> 3) + 32 * it;
      const int nn4 = (t & 7) * 4;
      const int gn  = nb + kb + nn4;
      float4 v = (gn < NTOT)
          ? *(const float4*)(xt + (size_t)(b * 256 + c0 + c_l) * NTOT + gn)
          : make_float4(0.f, 0.f, 0.f, 0.f);
      As[nn4 + 0][c_l] = v.x; As[nn4 + 1][c_l] = v.y;
      As[nn4 + 2][c_l] = v.z; As[nn4 + 3][c_l] = v.w;
    }
#pragma unroll
    for (int it = 0; it < 2; ++it) {
      const int nn  = (t >> 4) + 16 * it;
      const int kk4 = (t & 15) * 4;
      const int gn  = nb + kb + nn;
      float4 v = (gn < NTOT)
          ? *(const float4*)(z + ((size_t)b * NTOT + gn) * 64 + kk4)
          : make_float4(0.f, 0.f, 0.f, 0.f);
      *(float4*)&Bs[nn][kk4] = v;
    }
    __syncthreads();
#pragma unroll
    for (int nn = 0; nn < 32; ++nn) {
      float4 a0 = *(const float4*)&As[nn][tc * 8];
      float4 a1 = *(const float4*)&As[nn][tc * 8 + 4];
      float4 bz = *(const float4*)&Bs[nn][tk * 4];
      float av[8] = {a0.x, a0.y, a0.z, a0.w, a1.x, a1.y, a1.z, a1.w};
      float bv[4] = {bz.x, bz.y, bz.z, bz.w};
#pragma unroll
      for (int i = 0; i < 8; ++i)
#pragma unroll
        for (int j = 0; j < 4; ++j)
          acc[i][j] = fmaf(av[i], bv[j], acc[i][j]);
    }
    __syncthreads();
  }

#pragma unroll
  for (int j = 0; j < 4; ++j) {
    const int k = tk * 4 + j;
    float4 v0 = make_float4(acc[0][j], acc[1][j], acc[2][j], acc[3][j]);
    float4 v1 = make_float4(acc[4][j], acc[5][j], acc[6][j], acc[7][j]);
    size_t base = (((size_t)b * 17 + ch) * 64 + k) * 256 + c0 + tc * 8;
    *(float4*)(part + base)     = v0;
    *(float4*)(part + base + 4) = v1;
  }
}

// ---------------------------------------------------------------------------
// mu reduce + l2norm over c. block = (k, b), 256 threads = c.
// ---------------------------------------------------------------------------
__global__ __launch_bounds__(256)
void mu_reduce_kernel(const float* __restrict__ part, float* __restrict__ mu_ws,
                      float* __restrict__ mu_out)
{
  const int k = blockIdx.x;
  const int b = blockIdx.y;
  const int c = threadIdx.x;
  float s = 0.f;
  for (int ch = 0; ch < 17; ++ch)
    s += part[(((size_t)b * 17 + ch) * 64 + k) * 256 + c];
  __shared__ float red[256];
  red[c] = s * s;
  __syncthreads();
  for (int off = 128; off > 0; off >>= 1) {
    if (c < off) red[c] += red[c + off];
    __syncthreads();
  }
  const float f   = 1.0f / (1e-6f + sqrtf(red[0]));
  const float val = s * f;
  mu_ws[((size_t)b * 256 + c) * 64 + k] = val;
  if (mu_out) mu_out[((size_t)b * 256 + c) * 64 + k] = val;
}

// ---------------------------------------------------------------------------
// x_rec[c,n] = relu( sum_k mu[c,k] * z[n,k] )  -> written into x_total buffer
// tile: 64 c x 128 n, thread = 4c x 8n, K = 64 single pass.
// zs columns XOR-swizzled by row-group to kill bank conflicts.
// ---------------------------------------------------------------------------
__global__ __launch_bounds__(256)
void xrec_kernel(const float* __restrict__ mu, const float* __restrict__ z,
                 float* __restrict__ xrec)
{
  __shared__ float zs[128][68];  // [nn][k^swz]
  __shared__ float ms[64][68];   // [c_l][k]
  const int t  = threadIdx.x;
  const int n0 = blockIdx.x * 128;
  const int c0 = blockIdx.y * 64;
  const int b  = blockIdx.z;
  const int tn = t & 15, tc = t >> 4;

#pragma unroll
  for (int it = 0; it < 8; ++it) {
    const int nn  = (t >> 4) + 16 * it;
    const int kk4 = (t & 15) * 4;
    const int gn  = n0 + nn;
    float4 v = (gn < NTOT)
        ? *(const float4*)(z + ((size_t)b * NTOT + gn) * 64 + kk4)
        : make_float4(0.f, 0.f, 0.f, 0.f);
    const int col = kk4 ^ (((nn >> 3) & 7) << 2);
    *(float4*)&zs[nn][col] = v;
  }
#pragma unroll
  for (int it = 0; it < 4; ++it) {
    const int c_l = (t >> 4) + 16 * it;
    const int kk4 = (t & 15) * 4;
    float4 v = *(const float4*)(mu + ((size_t)b * 256 + c0 + c_l) * 64 + kk4);
    *(float4*)&ms[c_l][kk4] = v;
  }
  __syncthreads();

  float acc[4][8];
#pragma unroll
  for (int i = 0; i < 4; ++i)
#pragma unroll
    for (int r = 0; r < 8; ++r) acc[i][r] = 0.f;

  const int swz = (tn & 7) << 2;
#pragma unroll
  for (int kk4 = 0; kk4 < 64; kk4 += 4) {
    float4 a_[4]; float4 b_[8];
#pragma unroll
    for (int i = 0; i < 4; ++i) a_[i] = *(const float4*)&ms[tc * 4 + i][kk4];
#pragma unroll
    for (int r = 0; r < 8; ++r) b_[r] = *(const float4*)&zs[tn * 8 + r][kk4 ^ swz];
#pragma unroll
    for (int i = 0; i < 4; ++i)
#pragma unroll
      for (int r = 0; r < 8; ++r) {
        acc[i][r] = fmaf(a_[i].x, b_[r].x, acc[i][r]);
        acc[i][r] = fmaf(a_[i].y, b_[r].y, acc[i][r]);
        acc[i][r] = fmaf(a_[i].z, b_[r].z, acc[i][r]);
        acc[i][r] = fmaf(a_[i].w, b_[r].w, acc[i][r]);
      }
  }

#pragma unroll
  for (int i = 0; i < 4; ++i) {
    const int cc = c0 + tc * 4 + i;
#pragma unroll
    for (int jj = 0; jj < 8; jj += 4) {
      const int gn = n0 + tn * 8 + jj;
      if (gn >= NTOT) continue;
      float4 r = make_float4(fmaxf(acc[i][jj + 0], 0.f), fmaxf(acc[i][jj + 1], 0.f),
                             fmaxf(acc[i][jj + 2], 0.f), fmaxf(acc[i][jj + 3], 0.f));
      *(float4*)(xrec + (size_t)(b * 256 + cc) * NTOT + gn) = r;
    }
  }
}

// ---------------------------------------------------------------------------
extern "C" void kernel_launch(void* const* d_in, const int* in_sizes, int n_in,
                              void* d_out, int out_size, void* d_ws, size_t ws_size,
                              hipStream_t stream)
{
  const float* x0   = (const float*)d_in[0];
  const float* x1   = (const float*)d_in[1];
  const float* x2   = (const float*)d_in[2];
  const float* x3   = (const float*)d_in[3];
  const float* w1   = (const float*)d_in[4];
  const float* b1   = (const float*)d_in[5];
  const float* w2   = (const float*)d_in[6];
  const float* bn_g = (const float*)d_in[7];
  const float* bn_b = (const float*)d_in[8];
  const float* bn_m = (const float*)d_in[9];
  const float* bn_v = (const float*)d_in[10];
  const float* mu0  = (const float*)d_in[11];
  float* out = (float*)d_out;

  float* xt   = (float*)d_ws;              // 16*256*8500   = 34,816,000 f
  float* z    = xt   + 34816000ull;        // 16*8500*64    =  8,704,000 f
  float* part = z    + 8704000ull;         // 16*17*64*256  =  4,456,448 f
  float* muws = part + 4456448ull;         // 16*256*64     =    262,144 f

  dim3 gconv(67, 4, 16);
  conv_kernel<0><<<gconv, 256, 0, stream>>>(w1, b1, x0, x1, x2, x3,
                                            nullptr, nullptr, nullptr, nullptr,
                                            nullptr, xt);
  for (int s = 0; s < 3; ++s) {
    z_kernel<<<dim3(67, 16), 256, 0, stream>>>(xt, s == 0 ? mu0 : muws,
                                               s == 0 ? 0 : 1, z);
    mu_part_kernel<<<dim3(17, 2, 16), 256, 0, stream>>>(xt, z, part);
    mu_reduce_kernel<<<dim3(64, 16), 256, 0, stream>>>(
        part, muws, (s == 2) ? (out + 34816000ull) : nullptr);
  }
  xrec_kernel<<<dim3(67, 4, 16), 256, 0, stream>>>(muws, z, xt);
  conv_kernel<1><<<gconv, 256, 0, stream>>>(w2, nullptr, x0, x1, x2, x3,
                                            xt, bn_g, bn_b, bn_m, bn_v, out);
}

// Round 6
// 1232.077 us; speedup vs baseline: 2.3292x; 2.3292x over previous
//
#include <hip/hip_runtime.h>
#include <math.h>

#define NTOT 8500

// ---------------------------------------------------------------------------
// Geometry: 4 scales concatenated along n: [6400 | 1600 | 400 | 100] = 8500.
// All boundaries divisible by 4 -> float4 loads never straddle scales.
// ---------------------------------------------------------------------------
__device__ __forceinline__ size_t in_index(int gn, int bc, int* which) {
  if (gn < 6400) { *which = 0; return (size_t)bc * 6400 + gn; }
  if (gn < 8000) { *which = 1; return (size_t)bc * 1600 + (gn - 6400); }
  if (gn < 8400) { *which = 2; return (size_t)bc * 400  + (gn - 8000); }
  *which = 3;     return (size_t)bc * 100  + (gn - 8400);
}

// ---------------------------------------------------------------------------
// conv kernel: per batch GEMM  out[o,n] = sum_c W[o,c] * X[c,n]  (+ epilogue)
// WHICH=0: conv1, X gathered from 4 input scales, +bias, write x_total
// WHICH=1: conv2, X = x_rec (contiguous), epilogue BN + residual + relu,
//          scattered writes into the 4 output scale segments of d_out
// tile: 64 (o) x 128 (n), 256 threads, thread = 4x8, K-chunks of 32
// ---------------------------------------------------------------------------
template <int WHICH>
__global__ __launch_bounds__(256)
void conv_kernel(const float* __restrict__ W, const float* __restrict__ bias,
                 const float* __restrict__ x0, const float* __restrict__ x1,
                 const float* __restrict__ x2, const float* __restrict__ x3,
                 const float* __restrict__ xrec,
                 const float* __restrict__ bn_g, const float* __restrict__ bn_b,
                 const float* __restrict__ bn_m, const float* __restrict__ bn_v,
                 float* __restrict__ out)
{
  __shared__ float As[32][68];    // [kk][o]
  __shared__ float Bs[32][132];   // [kk][n]
  const int t  = threadIdx.x;
  const int n0 = blockIdx.x * 128;
  const int m0 = blockIdx.y * 64;
  const int b  = blockIdx.z;
  const int tm = t & 15, tn = t >> 4;

  float acc[4][8];
#pragma unroll
  for (int i = 0; i < 4; ++i)
#pragma unroll
    for (int j = 0; j < 8; ++j) acc[i][j] = 0.f;

  for (int k0 = 0; k0 < 256; k0 += 32) {
#pragma unroll
    for (int it = 0; it < 2; ++it) {
      const int o_l = (t >> 3) + 32 * it;
      const int kk4 = (t & 7) * 4;
      float4 v = *(const float4*)(W + (size_t)(m0 + o_l) * 256 + k0 + kk4);
      As[kk4 + 0][o_l] = v.x; As[kk4 + 1][o_l] = v.y;
      As[kk4 + 2][o_l] = v.z; As[kk4 + 3][o_l] = v.w;
    }
#pragma unroll
    for (int it = 0; it < 4; ++it) {
      const int kk  = (t >> 5) + 8 * it;
      const int nn4 = (t & 31) * 4;
      const int gn  = n0 + nn4;
      float4 v = make_float4(0.f, 0.f, 0.f, 0.f);
      if (gn < NTOT) {
        if (WHICH == 0) {
          int w_; size_t idx = in_index(gn, b * 256 + k0 + kk, &w_);
          const float* src = (w_ == 0) ? x0 : (w_ == 1) ? x1 : (w_ == 2) ? x2 : x3;
          v = *(const float4*)(src + idx);
        } else {
          v = *(const float4*)(xrec + (size_t)(b * 256 + k0 + kk) * NTOT + gn);
        }
      }
      *(float4*)&Bs[kk][nn4] = v;
    }
    __syncthreads();
#pragma unroll
    for (int kk = 0; kk < 32; ++kk) {
      float4 a = *(const float4*)&As[kk][tm * 4];
      float4 p = *(const float4*)&Bs[kk][tn * 8];
      float4 q = *(const float4*)&Bs[kk][tn * 8 + 4];
      float av[4] = {a.x, a.y, a.z, a.w};
      float bv[8] = {p.x, p.y, p.z, p.w, q.x, q.y, q.z, q.w};
#pragma unroll
      for (int i = 0; i < 4; ++i)
#pragma unroll
        for (int j = 0; j < 8; ++j)
          acc[i][j] = fmaf(av[i], bv[j], acc[i][j]);
    }
    __syncthreads();
  }

#pragma unroll
  for (int i = 0; i < 4; ++i) {
    const int o = m0 + tm * 4 + i;
    float addb = 0.f, isf = 0.f, shf = 0.f;
    if (WHICH == 0) {
      addb = bias[o];
    } else {
      float g = bn_g[o];
      isf = g / sqrtf(bn_v[o] + 1e-5f);
      shf = bn_b[o] - bn_m[o] * isf;
    }
#pragma unroll
    for (int jj = 0; jj < 8; jj += 4) {
      const int gn = n0 + tn * 8 + jj;
      if (gn >= NTOT) continue;
      float4 r = make_float4(acc[i][jj + 0], acc[i][jj + 1],
                             acc[i][jj + 2], acc[i][jj + 3]);
      if (WHICH == 0) {
        r.x += addb; r.y += addb; r.z += addb; r.w += addb;
        *(float4*)(out + (size_t)(b * 256 + o) * NTOT + gn) = r;
      } else {
        int w_; size_t idx = in_index(gn, b * 256 + o, &w_);
        const float* src = (w_ == 0) ? x0 : (w_ == 1) ? x1 : (w_ == 2) ? x2 : x3;
        float4 rv = *(const float4*)(src + idx);
        size_t ob = (w_ == 0) ? 0ull : (w_ == 1) ? 26214400ull
                  : (w_ == 2) ? 32768000ull : 34406400ull;
        r.x = fmaxf(fmaf(r.x, isf, shf) + rv.x, 0.f);
        r.y = fmaxf(fmaf(r.y, isf, shf) + rv.y, 0.f);
        r.z = fmaxf(fmaf(r.z, isf, shf) + rv.z, 0.f);
        r.w = fmaxf(fmaf(r.w, isf, shf) + rv.w, 0.f);
        *(float4*)(out + ob + idx) = r;
      }
    }
  }
}

// ---------------------------------------------------------------------------
// z kernel: z[n,k] = softmax_k( sum_c xt[c,n] * mu[c,k] )
// tile: 128 n x 64 k, 256 threads, thread = 8n x 4k; row lanes contiguous
// (tk = t&15) so softmax reduces with 16-lane shuffles.
// ---------------------------------------------------------------------------
__global__ __launch_bounds__(256)
void z_kernel(const float* __restrict__ xt, const float* __restrict__ mu,
              int mu_per_batch, float* __restrict__ zbuf)
{
  __shared__ float xs[32][136];  // [cc][n]
  __shared__ float mus[32][68];  // [cc][k]
  const int t  = threadIdx.x;
  const int n0 = blockIdx.x * 128;
  const int b  = blockIdx.y;
  const float* mub = mu + (mu_per_batch ? (size_t)b * 256 * 64 : 0);
  const int tk = t & 15, tn = t >> 4;

  float acc[8][4];
#pragma unroll
  for (int r = 0; r < 8; ++r)
#pragma unroll
    for (int j = 0; j < 4; ++j) acc[r][j] = 0.f;

  for (int c0 = 0; c0 < 256; c0 += 32) {
#pragma unroll
    for (int it = 0; it < 4; ++it) {
      const int cc  = (t >> 5) + 8 * it;
      const int nn4 = (t & 31) * 4;
      const int gn  = n0 + nn4;
      float4 v = (gn < NTOT)
          ? *(const float4*)(xt + (size_t)(b * 256 + c0 + cc) * NTOT + gn)
          : make_float4(0.f, 0.f, 0.f, 0.f);
      *(float4*)&xs[cc][nn4] = v;
    }
#pragma unroll
    for (int it = 0; it < 2; ++it) {
      const int cc  = (t >> 4) + 16 * it;
      const int kk4 = (t & 15) * 4;
      float4 v = *(const float4*)(mub + (size_t)(c0 + cc) * 64 + kk4);
      *(float4*)&mus[cc][kk4] = v;
    }
    __syncthreads();
#pragma unroll
    for (int cc = 0; cc < 32; ++cc) {
      float4 m4 = *(const float4*)&mus[cc][tk * 4];
      float4 xa = *(const float4*)&xs[cc][tn * 8];
      float4 xb = *(const float4*)&xs[cc][tn * 8 + 4];
      float xv[8] = {xa.x, xa.y, xa.z, xa.w, xb.x, xb.y, xb.z, xb.w};
      float mv[4] = {m4.x, m4.y, m4.z, m4.w};
#pragma unroll
      for (int r = 0; r < 8; ++r)
#pragma unroll
        for (int j = 0; j < 4; ++j)
          acc[r][j] = fmaf(xv[r], mv[j], acc[r][j]);
    }
    __syncthreads();
  }

#pragma unroll
  for (int r = 0; r < 8; ++r) {
    float mx = fmaxf(fmaxf(acc[r][0], acc[r][1]), fmaxf(acc[r][2], acc[r][3]));
#pragma unroll
    for (int off = 8; off >= 1; off >>= 1) mx = fmaxf(mx, __shfl_xor(mx, off));
    float e0 = __expf(acc[r][0] - mx), e1 = __expf(acc[r][1] - mx);
    float e2 = __expf(acc[r][2] - mx), e3 = __expf(acc[r][3] - mx);
    float s = e0 + e1 + e2 + e3;
#pragma unroll
    for (int off = 8; off >= 1; off >>= 1) s += __shfl_xor(s, off);
    const float inv = 1.0f / s;
    const int gn = n0 + tn * 8 + r;
    if (gn < NTOT) {
      float4 w = make_float4(e0 * inv, e1 * inv, e2 * inv, e3 * inv);
      *(float4*)(zbuf + ((size_t)b * NTOT + gn) * 64 + tk * 4) = w;
    }
  }
}

// ---------------------------------------------------------------------------
// mu partial: part[b,ch,k,c] = sum_{n in chunk} xt[c,n] * z[n,k]
// (z-colsum normalization cancels in the downstream l2norm -> skipped)
// tile: 128 c x 64 k, 256 threads, thread = 8c x 4k, chunk = 512 n
// ---------------------------------------------------------------------------
__global__ __launch_bounds__(256)
void mu_part_kernel(const float* __restrict__ xt, const float* __restrict__ z,
                    float* __restrict__ part)
{
  __shared__ float As[32][132];  // [nn][c]
  __shared__ float Bs[32][68];   // [nn][k]
  const int t  = threadIdx.x;
  const int ch = blockIdx.x;         // 0..16
  const int c0 = blockIdx.y * 128;   // 0,128
  const int b  = blockIdx.z;
  const int nb = ch * 512;
  const int tk = t & 15, tc = t >> 4;

  float acc[8][4];
#pragma unroll
  for (int i = 0; i < 8; ++i)
#pragma unroll
    for (int j = 0; j < 4; ++j) acc[i][j] = 0.f;

  for (int kb = 0; kb < 512; kb += 32) {
#pragma unroll
    for (int it = 0; it < 4; ++it) {
      const int c_l = (t >> 3) + 32 * it;
      const int nn4 = (t & 7) * 4;
      const int gn  = nb + kb + nn4;
      float4 v = (gn < NTOT)
          ? *(const float4*)(xt + (size_t)(b * 256 + c0 + c_l) * NTOT + gn)
          : make_float4(0.f, 0.f, 0.f, 0.f);
      As[nn4 + 0][c_l] = v.x; As[nn4 + 1][c_l] = v.y;
      As[nn4 + 2][c_l] = v.z; As[nn4 + 3][c_l] = v.w;
    }
#pragma unroll
    for (int it = 0; it < 2; ++it) {
      const int nn  = (t >> 4) + 16 * it;
      const int kk4 = (t & 15) * 4;
      const int gn  = nb + kb + nn;
      float4 v = (gn < NTOT)
          ? *(const float4*)(z + ((size_t)b * NTOT + gn) * 64 + kk4)
          : make_float4(0.f, 0.f, 0.f, 0.f);
      *(float4*)&Bs[nn][kk4] = v;
    }
    __syncthreads();
#pragma unroll
    for (int nn = 0; nn < 32; ++nn) {
      float4 a0 = *(const float4*)&As[nn][tc * 8];
      float4 a1 = *(const float4*)&As[nn][tc * 8 + 4];
      float4 bz = *(const float4*)&Bs[nn][tk * 4];
      float av[8] = {a0.x, a0.y, a0.z, a0.w, a1.x, a1.y, a1.z, a1.w};
      float bv[4] = {bz.x, bz.y, bz.z, bz.w};
#pragma unroll
      for (int i = 0; i < 8; ++i)
#pragma unroll
        for (int j = 0; j < 4; ++j)
          acc[i][j] = fmaf(av[i], bv[j], acc[i][j]);
    }
    __syncthreads();
  }

#pragma unroll
  for (int j = 0; j < 4; ++j) {
    const int k = tk * 4 + j;
    float4 v0 = make_float4(acc[0][j], acc[1][j], acc[2][j], acc[3][j]);
    float4 v1 = make_float4(acc[4][j], acc[5][j], acc[6][j], acc[7][j]);
    size_t base = (((size_t)b * 17 + ch) * 64 + k) * 256 + c0 + tc * 8;
    *(float4*)(part + base)     = v0;
    *(float4*)(part + base + 4) = v1;
  }
}

// ---------------------------------------------------------------------------
// mu reduce + l2norm over c. block = (k, b), 256 threads = c.
// ---------------------------------------------------------------------------
__global__ __launch_bounds__(256)
void mu_reduce_kernel(const float* __restrict__ part, float* __restrict__ mu_ws,
                      float* __restrict__ mu_out)
{
  const int k = blockIdx.x;
  const int b = blockIdx.y;
  const int c = threadIdx.x;
  float s = 0.f;
  for (int ch = 0; ch < 17; ++ch)
    s += part[(((size_t)b * 17 + ch) * 64 + k) * 256 + c];
  __shared__ float red[256];
  red[c] = s * s;
  __syncthreads();
  for (int off = 128; off > 0; off >>= 1) {
    if (c < off) red[c] += red[c + off];
    __syncthreads();
  }
  const float f   = 1.0f / (1e-6f + sqrtf(red[0]));
  const float val = s * f;
  mu_ws[((size_t)b * 256 + c) * 64 + k] = val;
  if (mu_out) mu_out[((size_t)b * 256 + c) * 64 + k] = val;
}

// ---------------------------------------------------------------------------
// rec kernel (REWRITTEN round 3): x_rec[c,n] = relu( sum_k mu[c,k]*z[n,k] )
// Old version: fully-unrolled K=64 loop + float4 operand arrays -> VGPR=256,
// scratch spills, 3.9 GB HBM/dispatch, 1694 us (59% of total!).
// New version mirrors conv_kernel's proven K-chunked structure: chunks of 16
// with barriers, scalar operand arrays, bounded liveness.
// tile: 64 c x 128 n, 256 threads, thread = 4c x 8n, K-chunks of 16.
// ---------------------------------------------------------------------------
__global__ __launch_bounds__(256)
void rec_kernel(const float* __restrict__ mu, const float* __restrict__ z,
                float* __restrict__ xrec)
{
  __shared__ float As[16][68];    // [kk][c]
  __shared__ float Bs[16][132];   // [kk][n]
  const int t  = threadIdx.x;
  const int n0 = blockIdx.x * 128;
  const int c0 = blockIdx.y * 64;
  const int b  = blockIdx.z;
  const int tm = t & 15, tn = t >> 4;

  float acc[4][8];
#pragma unroll
  for (int i = 0; i < 4; ++i)
#pragma unroll
    for (int j = 0; j < 8; ++j) acc[i][j] = 0.f;

  for (int k0 = 0; k0 < 64; k0 += 16) {
    // A: mu[c0+0..63][k0+0..15], one float4 per thread (64B/4-lane group)
    {
      const int c_l = t >> 2;
      const int kk4 = (t & 3) * 4;
      float4 v = *(const float4*)(mu + ((size_t)(b * 256 + c0 + c_l)) * 64 + k0 + kk4);
      As[kk4 + 0][c_l] = v.x; As[kk4 + 1][c_l] = v.y;
      As[kk4 + 2][c_l] = v.z; As[kk4 + 3][c_l] = v.w;
    }
    // B: z[n0+0..127][k0+0..15], two float4 per thread
#pragma unroll
    for (int it = 0; it < 2; ++it) {
      const int nn  = (t >> 2) + 64 * it;
      const int kk4 = (t & 3) * 4;
      const int gn  = n0 + nn;
      float4 v = (gn < NTOT)
          ? *(const float4*)(z + ((size_t)b * NTOT + gn) * 64 + k0 + kk4)
          : make_float4(0.f, 0.f, 0.f, 0.f);
      Bs[kk4 + 0][nn] = v.x; Bs[kk4 + 1][nn] = v.y;
      Bs[kk4 + 2][nn] = v.z; Bs[kk4 + 3][nn] = v.w;
    }
    __syncthreads();
#pragma unroll
    for (int kk = 0; kk < 16; ++kk) {
      float4 a = *(const float4*)&As[kk][tm * 4];
      float4 p = *(const float4*)&Bs[kk][tn * 8];
      float4 q = *(const float4*)&Bs[kk][tn * 8 + 4];
      float av[4] = {a.x, a.y, a.z, a.w};
      float bv[8] = {p.x, p.y, p.z, p.w, q.x, q.y, q.z, q.w};
#pragma unroll
      for (int i = 0; i < 4; ++i)
#pragma unroll
        for (int j = 0; j < 8; ++j)
          acc[i][j] = fmaf(av[i], bv[j], acc[i][j]);
    }
    __syncthreads();
  }

#pragma unroll
  for (int i = 0; i < 4; ++i) {
    const int cc = c0 + tm * 4 + i;
#pragma unroll
    for (int jj = 0; jj < 8; jj += 4) {
      const int gn = n0 + tn * 8 + jj;
      if (gn >= NTOT) continue;
      float4 r = make_float4(fmaxf(acc[i][jj + 0], 0.f), fmaxf(acc[i][jj + 1], 0.f),
                             fmaxf(acc[i][jj + 2], 0.f), fmaxf(acc[i][jj + 3], 0.f));
      *(float4*)(xrec + (size_t)(b * 256 + cc) * NTOT + gn) = r;
    }
  }
}

// ---------------------------------------------------------------------------
extern "C" void kernel_launch(void* const* d_in, const int* in_sizes, int n_in,
                              void* d_out, int out_size, void* d_ws, size_t ws_size,
                              hipStream_t stream)
{
  const float* x0   = (const float*)d_in[0];
  const float* x1   = (const float*)d_in[1];
  const float* x2   = (const float*)d_in[2];
  const float* x3   = (const float*)d_in[3];
  const float* w1   = (const float*)d_in[4];
  const float* b1   = (const float*)d_in[5];
  const float* w2   = (const float*)d_in[6];
  const float* bn_g = (const float*)d_in[7];
  const float* bn_b = (const float*)d_in[8];
  const float* bn_m = (const float*)d_in[9];
  const float* bn_v = (const float*)d_in[10];
  const float* mu0  = (const float*)d_in[11];
  float* out = (float*)d_out;

  float* xt   = (float*)d_ws;              // 16*256*8500   = 34,816,000 f
  float* z    = xt   + 34816000ull;        // 16*8500*64    =  8,704,000 f
  float* part = z    + 8704000ull;         // 16*17*64*256  =  4,456,448 f
  float* muws = part + 4456448ull;         // 16*256*64     =    262,144 f

  dim3 gconv(67, 4, 16);
  conv_kernel<0><<<gconv, 256, 0, stream>>>(w1, b1, x0, x1, x2, x3,
                                            nullptr, nullptr, nullptr, nullptr,
                                            nullptr, xt);
  for (int s = 0; s < 3; ++s) {
    z_kernel<<<dim3(67, 16), 256, 0, stream>>>(xt, s == 0 ? mu0 : muws,
                                               s == 0 ? 0 : 1, z);
    mu_part_kernel<<<dim3(17, 2, 16), 256, 0, stream>>>(xt, z, part);
    mu_reduce_kernel<<<dim3(64, 16), 256, 0, stream>>>(
        part, muws, (s == 2) ? (out + 34816000ull) : nullptr);
  }
  rec_kernel<<<dim3(67, 4, 16), 256, 0, stream>>>(muws, z, xt);
  conv_kernel<1><<<gconv, 256, 0, stream>>>(w2, nullptr, x0, x1, x2, x3,
                                            xt, bn_g, bn_b, bn_m, bn_v, out);
}